// Round 16
// baseline (3383.278 us; speedup 1.0000x reference)
//
#include <hip/hip_runtime.h>
#include <hip/hip_bf16.h>
#include <stdint.h>

// QuantLinear GPTQ 4-bit: out[8192,11008] = x[8192,4096] . W[4096,11008] + bias
// i8 path: W' = (q - z) exact in i8; x per-row i8; per-group(128) scales folded
// on i32 partials; row scale at epilogue.
// r16 = r13 but SINGLE-buffered LDS (32 KiB/block) -> 4 blocks/CU co-resident.
// Within a block the DMA can't overlap its own compute; across the 4
// independent blocks the CU's LDS pipe (the binding resource, ~294 us floor)
// stays fed. Registers identical to r13's verified no-spill config.
#define M_DIM 8192
#define K_DIM 4096
#define N_DIM 11008

typedef int i32x4 __attribute__((ext_vector_type(4)));
typedef float f32x4 __attribute__((ext_vector_type(4)));

typedef __attribute__((address_space(1))) const void global_cvoid;
typedef __attribute__((address_space(3))) void lds_void;

__device__ __forceinline__ void gload_lds16(const void* g, void* l) {
  // async global->LDS: each lane's 16B lands at lds_base + lane*16 (linear dest)
  __builtin_amdgcn_global_load_lds((global_cvoid*)g, (lds_void*)l, 16, 0, 0);
}

// ---------------- fused prep: quantize x (blocks < 8192) | unpack W (rest) ----------------
__global__ void k_prep(const float* __restrict__ x, signed char* __restrict__ xq,
                       float* __restrict__ sx, const int* __restrict__ qw,
                       const int* __restrict__ qz, signed char* __restrict__ wt) {
  if (blockIdx.x < M_DIM) {
    int m = blockIdx.x;
    int tx = threadIdx.x;                     // 256 threads, 16 floats each
    const float4* row = (const float4*)(x + (size_t)m * K_DIM);
    float4 v[4];
    float mx = 0.f;
    #pragma unroll
    for (int i = 0; i < 4; ++i) {
      v[i] = row[tx * 4 + i];
      mx = fmaxf(mx, fmaxf(fmaxf(fabsf(v[i].x), fabsf(v[i].y)),
                           fmaxf(fabsf(v[i].z), fabsf(v[i].w))));
    }
    #pragma unroll
    for (int off = 1; off < 64; off <<= 1)
      mx = fmaxf(mx, __shfl_xor(mx, off));
    __shared__ float wmx[4];
    if ((tx & 63) == 0) wmx[tx >> 6] = mx;
    __syncthreads();
    mx = fmaxf(fmaxf(wmx[0], wmx[1]), fmaxf(wmx[2], wmx[3]));
    mx = fmaxf(mx, 1e-20f);
    float scale = 127.0f / mx;
    if (tx == 0) sx[m] = mx / 127.0f;
    union { signed char c[16]; uint4 u; } p;
    #pragma unroll
    for (int i = 0; i < 4; ++i) {
      p.c[i * 4 + 0] = (signed char)(int)rintf(v[i].x * scale);
      p.c[i * 4 + 1] = (signed char)(int)rintf(v[i].y * scale);
      p.c[i * 4 + 2] = (signed char)(int)rintf(v[i].z * scale);
      p.c[i * 4 + 3] = (signed char)(int)rintf(v[i].w * scale);
    }
    ((uint4*)(xq + (size_t)m * K_DIM))[tx] = p.u;
  } else {
    int b = blockIdx.x - M_DIM;               // 2752 blocks: 43 n-blk x 64 k-blk
    int n = (b % 43) * 256 + threadIdx.x;
    int k8_0 = (b / 43) * 8;
    int g = (k8_0 * 8) >> 7;
    int zq = (qz[g * (N_DIM / 8) + (n >> 3)] >> ((n & 7) * 4)) & 15;
    #pragma unroll
    for (int i = 0; i < 8; ++i) {
      int k8 = k8_0 + i;
      int w = qw[(size_t)k8 * N_DIM + n];
      union { signed char c[8]; uint2 u; } r;
      #pragma unroll
      for (int j = 0; j < 8; ++j)
        r.c[j] = (signed char)(((w >> (4 * j)) & 15) - zq);
      *(uint2*)(wt + (size_t)n * K_DIM + (size_t)k8 * 8) = r.u;
    }
  }
}

// ---------------- i8 GEMM 128x128, BK=128, 4 waves, single-buf, 4 blocks/CU ----------------
// Per tile: vmcnt(0)+bar (staged tile ready) -> reads ks0 -> 16 MFMA (C=0) ->
// reads ks1 -> 16 MFMA -> fold -> bar (all reads done) -> stage next tile.
// Race-free: re-stage is after a barrier that follows all reads (each read's
// completion forced by its MFMA consumer); stage->read separated by
// vmcnt(0)+barrier at loop top.

#define MFMA_FIRST() do { \
  __builtin_amdgcn_s_setprio(1); \
  acci[0][0] = __builtin_amdgcn_mfma_i32_16x16x64_i8(af[0], bf[0], zq4, 0, 0, 0); \
  acci[0][1] = __builtin_amdgcn_mfma_i32_16x16x64_i8(af[0], bf[1], zq4, 0, 0, 0); \
  acci[0][2] = __builtin_amdgcn_mfma_i32_16x16x64_i8(af[0], bf[2], zq4, 0, 0, 0); \
  acci[0][3] = __builtin_amdgcn_mfma_i32_16x16x64_i8(af[0], bf[3], zq4, 0, 0, 0); \
  acci[1][0] = __builtin_amdgcn_mfma_i32_16x16x64_i8(af[1], bf[0], zq4, 0, 0, 0); \
  acci[1][1] = __builtin_amdgcn_mfma_i32_16x16x64_i8(af[1], bf[1], zq4, 0, 0, 0); \
  acci[1][2] = __builtin_amdgcn_mfma_i32_16x16x64_i8(af[1], bf[2], zq4, 0, 0, 0); \
  acci[1][3] = __builtin_amdgcn_mfma_i32_16x16x64_i8(af[1], bf[3], zq4, 0, 0, 0); \
  acci[2][0] = __builtin_amdgcn_mfma_i32_16x16x64_i8(af[2], bf[0], zq4, 0, 0, 0); \
  acci[2][1] = __builtin_amdgcn_mfma_i32_16x16x64_i8(af[2], bf[1], zq4, 0, 0, 0); \
  acci[2][2] = __builtin_amdgcn_mfma_i32_16x16x64_i8(af[2], bf[2], zq4, 0, 0, 0); \
  acci[2][3] = __builtin_amdgcn_mfma_i32_16x16x64_i8(af[2], bf[3], zq4, 0, 0, 0); \
  acci[3][0] = __builtin_amdgcn_mfma_i32_16x16x64_i8(af[3], bf[0], zq4, 0, 0, 0); \
  acci[3][1] = __builtin_amdgcn_mfma_i32_16x16x64_i8(af[3], bf[1], zq4, 0, 0, 0); \
  acci[3][2] = __builtin_amdgcn_mfma_i32_16x16x64_i8(af[3], bf[2], zq4, 0, 0, 0); \
  acci[3][3] = __builtin_amdgcn_mfma_i32_16x16x64_i8(af[3], bf[3], zq4, 0, 0, 0); \
  __builtin_amdgcn_s_setprio(0); \
} while (0)

#define MFMA_SECOND() do { \
  __builtin_amdgcn_s_setprio(1); \
  acci[0][0] = __builtin_amdgcn_mfma_i32_16x16x64_i8(af[0], bf[0], acci[0][0], 0, 0, 0); \
  acci[0][1] = __builtin_amdgcn_mfma_i32_16x16x64_i8(af[0], bf[1], acci[0][1], 0, 0, 0); \
  acci[0][2] = __builtin_amdgcn_mfma_i32_16x16x64_i8(af[0], bf[2], acci[0][2], 0, 0, 0); \
  acci[0][3] = __builtin_amdgcn_mfma_i32_16x16x64_i8(af[0], bf[3], acci[0][3], 0, 0, 0); \
  acci[1][0] = __builtin_amdgcn_mfma_i32_16x16x64_i8(af[1], bf[0], acci[1][0], 0, 0, 0); \
  acci[1][1] = __builtin_amdgcn_mfma_i32_16x16x64_i8(af[1], bf[1], acci[1][1], 0, 0, 0); \
  acci[1][2] = __builtin_amdgcn_mfma_i32_16x16x64_i8(af[1], bf[2], acci[1][2], 0, 0, 0); \
  acci[1][3] = __builtin_amdgcn_mfma_i32_16x16x64_i8(af[1], bf[3], acci[1][3], 0, 0, 0); \
  acci[2][0] = __builtin_amdgcn_mfma_i32_16x16x64_i8(af[2], bf[0], acci[2][0], 0, 0, 0); \
  acci[2][1] = __builtin_amdgcn_mfma_i32_16x16x64_i8(af[2], bf[1], acci[2][1], 0, 0, 0); \
  acci[2][2] = __builtin_amdgcn_mfma_i32_16x16x64_i8(af[2], bf[2], acci[2][2], 0, 0, 0); \
  acci[2][3] = __builtin_amdgcn_mfma_i32_16x16x64_i8(af[2], bf[3], acci[2][3], 0, 0, 0); \
  acci[3][0] = __builtin_amdgcn_mfma_i32_16x16x64_i8(af[3], bf[0], acci[3][0], 0, 0, 0); \
  acci[3][1] = __builtin_amdgcn_mfma_i32_16x16x64_i8(af[3], bf[1], acci[3][1], 0, 0, 0); \
  acci[3][2] = __builtin_amdgcn_mfma_i32_16x16x64_i8(af[3], bf[2], acci[3][2], 0, 0, 0); \
  acci[3][3] = __builtin_amdgcn_mfma_i32_16x16x64_i8(af[3], bf[3], acci[3][3], 0, 0, 0); \
  __builtin_amdgcn_s_setprio(0); \
} while (0)

// A(4) + B(4) fragments for ks-slice (byte ^= ks*64 walks slot)
#define LOADF(ks) do { \
  af[0] = *(const i32x4*)(const void*)(sh + (aoff0 ^ ((ks) << 6))); \
  af[1] = *(const i32x4*)(const void*)(sh + (aoff1 ^ ((ks) << 6))); \
  af[2] = *(const i32x4*)(const void*)(sh + (aoff2 ^ ((ks) << 6))); \
  af[3] = *(const i32x4*)(const void*)(sh + (aoff3 ^ ((ks) << 6))); \
  bf[0] = *(const i32x4*)(const void*)(sh + 16384 + (boff0 ^ ((ks) << 6))); \
  bf[1] = *(const i32x4*)(const void*)(sh + 16384 + (boff1 ^ ((ks) << 6))); \
  bf[2] = *(const i32x4*)(const void*)(sh + 16384 + (boff2 ^ ((ks) << 6))); \
  bf[3] = *(const i32x4*)(const void*)(sh + 16384 + (boff3 ^ ((ks) << 6))); \
} while (0)

// stage tile kt: 4 A-gloads + 4 B-gloads per wave
#define STAGE_ALL(kt) do { \
  unsigned char* la_ = sh + w * 4096; \
  unsigned char* lb_ = la_ + 16384; \
  gload_lds16(pA + (size_t)(kt) * 128, la_); \
  gload_lds16(pA + 8 * (size_t)K_DIM + (size_t)(kt) * 128, la_ + 1024); \
  gload_lds16(pA + 16 * (size_t)K_DIM + (size_t)(kt) * 128, la_ + 2048); \
  gload_lds16(pA + 24 * (size_t)K_DIM + (size_t)(kt) * 128, la_ + 3072); \
  gload_lds16(pB + (size_t)(kt) * 128, lb_); \
  gload_lds16(pB + 8 * (size_t)K_DIM + (size_t)(kt) * 128, lb_ + 1024); \
  gload_lds16(pB + 16 * (size_t)K_DIM + (size_t)(kt) * 128, lb_ + 2048); \
  gload_lds16(pB + 24 * (size_t)K_DIM + (size_t)(kt) * 128, lb_ + 3072); \
} while (0)

#define WAIT_VM0 asm volatile("s_waitcnt vmcnt(0)" ::: "memory")
#define BAR() do { __builtin_amdgcn_s_barrier(); asm volatile("" ::: "memory"); } while (0)

__global__ __launch_bounds__(256, 4) void k_gemm8(const signed char* __restrict__ xq,
                                                  const signed char* __restrict__ wq,
                                                  const float* __restrict__ sc,
                                                  const float* __restrict__ sx,
                                                  const float* __restrict__ bias,
                                                  float* __restrict__ out) {
  __shared__ __align__(16) unsigned char sh[32768];  // 32 KiB single buffer

  const int nwg = gridDim.x;                 // 5504, % 8 == 0 -> bijective
  int bid = blockIdx.x;
  int swz = (bid & 7) * (nwg >> 3) + (bid >> 3);
  const int ntn = N_DIM / 128;               // 86
  int mt = swz / ntn;                        // 0..63 (M tiles of 128)
  int nt = swz % ntn;                        // 0..85 (N tiles of 128)

  const int tid = threadIdx.x;
  const int w = tid >> 6;        // wave 0..3
  const int lane = tid & 63;
  const int wm = w >> 1;         // 0..1: M half (64 rows)
  const int wn = w & 1;          // 0..1: N half (64 cols)
  const int fr = lane & 15;
  const int fq = lane >> 4;
  const int r7 = fr & 7;

  // staging source: per-lane pre-swizzled (involution slot^row), rows of 128 B
  const int srow = lane >> 3;                 // 0..7
  const int sslot = (lane & 7) ^ srow;        // 16B slot within the 128B row
  const size_t goff = (size_t)srow * K_DIM + (size_t)sslot * 16;
  const signed char* pA = xq + (size_t)(mt * 128 + w * 32) * K_DIM + goff;
  const signed char* pB = wq + (size_t)(nt * 128 + w * 32) * K_DIM + goff;

  // fragment byte offsets (ks0); ks1 = ^64 (slot = (ks*4+fq) ^ r7)
  const int swb = (fq ^ r7) << 4;
  const int aoff0 = (wm * 64 + 0 * 16 + fr) * 128 + swb;
  const int aoff1 = (wm * 64 + 1 * 16 + fr) * 128 + swb;
  const int aoff2 = (wm * 64 + 2 * 16 + fr) * 128 + swb;
  const int aoff3 = (wm * 64 + 3 * 16 + fr) * 128 + swb;
  const int boff0 = (wn * 64 + 0 * 16 + fr) * 128 + swb;
  const int boff1 = (wn * 64 + 1 * 16 + fr) * 128 + swb;
  const int boff2 = (wn * 64 + 2 * 16 + fr) * 128 + swb;
  const int boff3 = (wn * 64 + 3 * 16 + fr) * 128 + swb;

  const int c0 = nt * 128 + wn * 64 + fr;    // this lane's base output column

  i32x4 acci[4][4];                          // written by MFMA_FIRST each tile
  f32x4 accf[4][4] = {};
  i32x4 af[4], bf[4];
  const i32x4 zq4 = {0, 0, 0, 0};

  // prologue: stage tile 0
  STAGE_ALL(0);

  for (int t = 0; t < 32; ++t) {
    WAIT_VM0;      // staged tile landed
    BAR();
    // group scales for this tile (group == tile since BK = 128 = GROUPSIZE)
    float sg0 = sc[(size_t)t * N_DIM + c0 + 0];
    float sg1 = sc[(size_t)t * N_DIM + c0 + 16];
    float sg2 = sc[(size_t)t * N_DIM + c0 + 32];
    float sg3 = sc[(size_t)t * N_DIM + c0 + 48];
    LOADF(0);
    MFMA_FIRST();
    LOADF(1);
    MFMA_SECOND();
    // group end: scale i32 partials into f32 accumulators
    #pragma unroll
    for (int mi = 0; mi < 4; ++mi) {
      #pragma unroll
      for (int r = 0; r < 4; ++r) {
        accf[mi][0][r] += sg0 * (float)acci[mi][0][r];
        accf[mi][1][r] += sg1 * (float)acci[mi][1][r];
        accf[mi][2][r] += sg2 * (float)acci[mi][2][r];
        accf[mi][3][r] += sg3 * (float)acci[mi][3][r];
      }
    }
    BAR();         // all waves' reads of this tile complete
    if (t < 31) STAGE_ALL(t + 1);   // safe to overwrite
  }

  // epilogue: C/D layout col=lane&15, row=(lane>>4)*4+reg; out = sx[m]*accf + bias
  const int r0 = mt * 128 + wm * 64 + fq * 4;
  #pragma unroll
  for (int mi = 0; mi < 4; ++mi) {
    float sxr[4];
    #pragma unroll
    for (int r = 0; r < 4; ++r) sxr[r] = sx[r0 + mi * 16 + r];
    #pragma unroll
    for (int nj = 0; nj < 4; ++nj) {
      int col = c0 + nj * 16;
      float bv = bias[col];
      size_t base = (size_t)(r0 + mi * 16) * N_DIM + col;
      #pragma unroll
      for (int r = 0; r < 4; ++r)
        out[base + (size_t)r * N_DIM] = sxr[r] * accf[mi][nj][r] + bv;
    }
  }
}

// ---------------- fallback (ws too small): naive fp32 ----------------
__global__ void k_fallback(const float* __restrict__ x, const int* __restrict__ qw,
                           const int* __restrict__ qz, const float* __restrict__ sc,
                           const float* __restrict__ bias, float* __restrict__ out) {
  int n = blockIdx.x * blockDim.x + threadIdx.x;
  int m = blockIdx.y;
  const float* xr = x + (size_t)m * K_DIM;
  float acc = 0.f;
  for (int g = 0; g < 32; ++g) {
    float s = sc[g * N_DIM + n];
    int zq = (qz[g * (N_DIM / 8) + (n >> 3)] >> ((n & 7) * 4)) & 15;
    float zs = s * (float)zq;
    for (int k8 = g * 16; k8 < g * 16 + 16; ++k8) {
      int w = qw[(size_t)k8 * N_DIM + n];
      #pragma unroll
      for (int j = 0; j < 8; ++j) {
        float wf = s * (float)((w >> (4 * j)) & 15) - zs;
        acc += wf * xr[k8 * 8 + j];
      }
    }
  }
  out[(size_t)m * N_DIM + n] = acc + bias[n];
}

extern "C" void kernel_launch(void* const* d_in, const int* in_sizes, int n_in,
                              void* d_out, int out_size, void* d_ws, size_t ws_size,
                              hipStream_t stream) {
  const float* x  = (const float*)d_in[0];
  const int* qw   = (const int*)d_in[1];
  const int* qz   = (const int*)d_in[2];
  const float* sc = (const float*)d_in[3];
  const float* bias = (const float*)d_in[4];
  float* out = (float*)d_out;

  const size_t xq_bytes = (size_t)M_DIM * K_DIM;          // 33,554,432
  const size_t sx_bytes = (size_t)M_DIM * sizeof(float);  // 32,768
  const size_t wq_bytes = (size_t)N_DIM * K_DIM;          // 45,088,768
  const size_t need = xq_bytes + sx_bytes + wq_bytes;

  if (ws_size >= need) {
    signed char* xq = (signed char*)d_ws;
    float* sx = (float*)((char*)d_ws + xq_bytes);
    signed char* wq = (signed char*)((char*)d_ws + xq_bytes + sx_bytes);
    k_prep<<<dim3(M_DIM + 2752), dim3(256), 0, stream>>>(x, xq, sx, qw, qz, wq);
    k_gemm8<<<dim3((M_DIM / 128) * (N_DIM / 128)), dim3(256), 0, stream>>>(xq, wq, sc, sx, bias, out);
  } else {
    k_fallback<<<dim3(N_DIM / 256, M_DIM), dim3(256), 0, stream>>>(x, qw, qz, sc, bias, out);
  }
}

// Round 17
// 591.438 us; speedup vs baseline: 5.7204x; 5.7204x over previous
//
#include <hip/hip_runtime.h>
#include <hip/hip_bf16.h>
#include <stdint.h>

// QuantLinear GPTQ 4-bit: out[8192,11008] = x[8192,4096] . W[4096,11008] + bias
// i8 path: W' = (q - z) exact in i8; x per-row i8; per-group(128) scales folded
// on i32 partials; row scale at epilogue.
// r17 = r16 (single-buffered 32 KiB LDS -> up to 5 blocks/CU) but with
// launch_bounds(256,2) -- r16's (256,4) clamped the allocator to 64 VGPR and
// spilled (WRITE 8.9 GB). With the verified ~96-VGPR allocation, residency is
// resource-limited (LDS 32K -> 5 blocks; VGPR 96 -> 5 waves/SIMD), not
// allocator-forced. Cross-block anti-phasing hides the single-buffer DMA gap.
#define M_DIM 8192
#define K_DIM 4096
#define N_DIM 11008

typedef int i32x4 __attribute__((ext_vector_type(4)));
typedef float f32x4 __attribute__((ext_vector_type(4)));

typedef __attribute__((address_space(1))) const void global_cvoid;
typedef __attribute__((address_space(3))) void lds_void;

__device__ __forceinline__ void gload_lds16(const void* g, void* l) {
  // async global->LDS: each lane's 16B lands at lds_base + lane*16 (linear dest)
  __builtin_amdgcn_global_load_lds((global_cvoid*)g, (lds_void*)l, 16, 0, 0);
}

// ---------------- fused prep: quantize x (blocks < 8192) | unpack W (rest) ----------------
__global__ void k_prep(const float* __restrict__ x, signed char* __restrict__ xq,
                       float* __restrict__ sx, const int* __restrict__ qw,
                       const int* __restrict__ qz, signed char* __restrict__ wt) {
  if (blockIdx.x < M_DIM) {
    int m = blockIdx.x;
    int tx = threadIdx.x;                     // 256 threads, 16 floats each
    const float4* row = (const float4*)(x + (size_t)m * K_DIM);
    float4 v[4];
    float mx = 0.f;
    #pragma unroll
    for (int i = 0; i < 4; ++i) {
      v[i] = row[tx * 4 + i];
      mx = fmaxf(mx, fmaxf(fmaxf(fabsf(v[i].x), fabsf(v[i].y)),
                           fmaxf(fabsf(v[i].z), fabsf(v[i].w))));
    }
    #pragma unroll
    for (int off = 1; off < 64; off <<= 1)
      mx = fmaxf(mx, __shfl_xor(mx, off));
    __shared__ float wmx[4];
    if ((tx & 63) == 0) wmx[tx >> 6] = mx;
    __syncthreads();
    mx = fmaxf(fmaxf(wmx[0], wmx[1]), fmaxf(wmx[2], wmx[3]));
    mx = fmaxf(mx, 1e-20f);
    float scale = 127.0f / mx;
    if (tx == 0) sx[m] = mx / 127.0f;
    union { signed char c[16]; uint4 u; } p;
    #pragma unroll
    for (int i = 0; i < 4; ++i) {
      p.c[i * 4 + 0] = (signed char)(int)rintf(v[i].x * scale);
      p.c[i * 4 + 1] = (signed char)(int)rintf(v[i].y * scale);
      p.c[i * 4 + 2] = (signed char)(int)rintf(v[i].z * scale);
      p.c[i * 4 + 3] = (signed char)(int)rintf(v[i].w * scale);
    }
    ((uint4*)(xq + (size_t)m * K_DIM))[tx] = p.u;
  } else {
    int b = blockIdx.x - M_DIM;               // 2752 blocks: 43 n-blk x 64 k-blk
    int n = (b % 43) * 256 + threadIdx.x;
    int k8_0 = (b / 43) * 8;
    int g = (k8_0 * 8) >> 7;
    int zq = (qz[g * (N_DIM / 8) + (n >> 3)] >> ((n & 7) * 4)) & 15;
    #pragma unroll
    for (int i = 0; i < 8; ++i) {
      int k8 = k8_0 + i;
      int w = qw[(size_t)k8 * N_DIM + n];
      union { signed char c[8]; uint2 u; } r;
      #pragma unroll
      for (int j = 0; j < 8; ++j)
        r.c[j] = (signed char)(((w >> (4 * j)) & 15) - zq);
      *(uint2*)(wt + (size_t)n * K_DIM + (size_t)k8 * 8) = r.u;
    }
  }
}

// ---------------- i8 GEMM 128x128, BK=128, 4 waves, single-buf ----------------
// Per tile: vmcnt(0)+bar (staged tile ready) -> reads ks0 -> 16 MFMA (C=0) ->
// reads ks1 -> 16 MFMA -> fold -> bar (all reads done) -> stage next tile.
// Race-free: re-stage is after a barrier that follows all reads (each read's
// completion forced by its MFMA consumer); stage->read separated by
// vmcnt(0)+barrier at loop top.

#define MFMA_FIRST() do { \
  __builtin_amdgcn_s_setprio(1); \
  acci[0][0] = __builtin_amdgcn_mfma_i32_16x16x64_i8(af[0], bf[0], zq4, 0, 0, 0); \
  acci[0][1] = __builtin_amdgcn_mfma_i32_16x16x64_i8(af[0], bf[1], zq4, 0, 0, 0); \
  acci[0][2] = __builtin_amdgcn_mfma_i32_16x16x64_i8(af[0], bf[2], zq4, 0, 0, 0); \
  acci[0][3] = __builtin_amdgcn_mfma_i32_16x16x64_i8(af[0], bf[3], zq4, 0, 0, 0); \
  acci[1][0] = __builtin_amdgcn_mfma_i32_16x16x64_i8(af[1], bf[0], zq4, 0, 0, 0); \
  acci[1][1] = __builtin_amdgcn_mfma_i32_16x16x64_i8(af[1], bf[1], zq4, 0, 0, 0); \
  acci[1][2] = __builtin_amdgcn_mfma_i32_16x16x64_i8(af[1], bf[2], zq4, 0, 0, 0); \
  acci[1][3] = __builtin_amdgcn_mfma_i32_16x16x64_i8(af[1], bf[3], zq4, 0, 0, 0); \
  acci[2][0] = __builtin_amdgcn_mfma_i32_16x16x64_i8(af[2], bf[0], zq4, 0, 0, 0); \
  acci[2][1] = __builtin_amdgcn_mfma_i32_16x16x64_i8(af[2], bf[1], zq4, 0, 0, 0); \
  acci[2][2] = __builtin_amdgcn_mfma_i32_16x16x64_i8(af[2], bf[2], zq4, 0, 0, 0); \
  acci[2][3] = __builtin_amdgcn_mfma_i32_16x16x64_i8(af[2], bf[3], zq4, 0, 0, 0); \
  acci[3][0] = __builtin_amdgcn_mfma_i32_16x16x64_i8(af[3], bf[0], zq4, 0, 0, 0); \
  acci[3][1] = __builtin_amdgcn_mfma_i32_16x16x64_i8(af[3], bf[1], zq4, 0, 0, 0); \
  acci[3][2] = __builtin_amdgcn_mfma_i32_16x16x64_i8(af[3], bf[2], zq4, 0, 0, 0); \
  acci[3][3] = __builtin_amdgcn_mfma_i32_16x16x64_i8(af[3], bf[3], zq4, 0, 0, 0); \
  __builtin_amdgcn_s_setprio(0); \
} while (0)

#define MFMA_SECOND() do { \
  __builtin_amdgcn_s_setprio(1); \
  acci[0][0] = __builtin_amdgcn_mfma_i32_16x16x64_i8(af[0], bf[0], acci[0][0], 0, 0, 0); \
  acci[0][1] = __builtin_amdgcn_mfma_i32_16x16x64_i8(af[0], bf[1], acci[0][1], 0, 0, 0); \
  acci[0][2] = __builtin_amdgcn_mfma_i32_16x16x64_i8(af[0], bf[2], acci[0][2], 0, 0, 0); \
  acci[0][3] = __builtin_amdgcn_mfma_i32_16x16x64_i8(af[0], bf[3], acci[0][3], 0, 0, 0); \
  acci[1][0] = __builtin_amdgcn_mfma_i32_16x16x64_i8(af[1], bf[0], acci[1][0], 0, 0, 0); \
  acci[1][1] = __builtin_amdgcn_mfma_i32_16x16x64_i8(af[1], bf[1], acci[1][1], 0, 0, 0); \
  acci[1][2] = __builtin_amdgcn_mfma_i32_16x16x64_i8(af[1], bf[2], acci[1][2], 0, 0, 0); \
  acci[1][3] = __builtin_amdgcn_mfma_i32_16x16x64_i8(af[1], bf[3], acci[1][3], 0, 0, 0); \
  acci[2][0] = __builtin_amdgcn_mfma_i32_16x16x64_i8(af[2], bf[0], acci[2][0], 0, 0, 0); \
  acci[2][1] = __builtin_amdgcn_mfma_i32_16x16x64_i8(af[2], bf[1], acci[2][1], 0, 0, 0); \
  acci[2][2] = __builtin_amdgcn_mfma_i32_16x16x64_i8(af[2], bf[2], acci[2][2], 0, 0, 0); \
  acci[2][3] = __builtin_amdgcn_mfma_i32_16x16x64_i8(af[2], bf[3], acci[2][3], 0, 0, 0); \
  acci[3][0] = __builtin_amdgcn_mfma_i32_16x16x64_i8(af[3], bf[0], acci[3][0], 0, 0, 0); \
  acci[3][1] = __builtin_amdgcn_mfma_i32_16x16x64_i8(af[3], bf[1], acci[3][1], 0, 0, 0); \
  acci[3][2] = __builtin_amdgcn_mfma_i32_16x16x64_i8(af[3], bf[2], acci[3][2], 0, 0, 0); \
  acci[3][3] = __builtin_amdgcn_mfma_i32_16x16x64_i8(af[3], bf[3], acci[3][3], 0, 0, 0); \
  __builtin_amdgcn_s_setprio(0); \
} while (0)

// A(4) + B(4) fragments for ks-slice (byte ^= ks*64 walks slot)
#define LOADF(ks) do { \
  af[0] = *(const i32x4*)(const void*)(sh + (aoff0 ^ ((ks) << 6))); \
  af[1] = *(const i32x4*)(const void*)(sh + (aoff1 ^ ((ks) << 6))); \
  af[2] = *(const i32x4*)(const void*)(sh + (aoff2 ^ ((ks) << 6))); \
  af[3] = *(const i32x4*)(const void*)(sh + (aoff3 ^ ((ks) << 6))); \
  bf[0] = *(const i32x4*)(const void*)(sh + 16384 + (boff0 ^ ((ks) << 6))); \
  bf[1] = *(const i32x4*)(const void*)(sh + 16384 + (boff1 ^ ((ks) << 6))); \
  bf[2] = *(const i32x4*)(const void*)(sh + 16384 + (boff2 ^ ((ks) << 6))); \
  bf[3] = *(const i32x4*)(const void*)(sh + 16384 + (boff3 ^ ((ks) << 6))); \
} while (0)

// stage tile kt: 4 A-gloads + 4 B-gloads per wave
#define STAGE_ALL(kt) do { \
  unsigned char* la_ = sh + w * 4096; \
  unsigned char* lb_ = la_ + 16384; \
  gload_lds16(pA + (size_t)(kt) * 128, la_); \
  gload_lds16(pA + 8 * (size_t)K_DIM + (size_t)(kt) * 128, la_ + 1024); \
  gload_lds16(pA + 16 * (size_t)K_DIM + (size_t)(kt) * 128, la_ + 2048); \
  gload_lds16(pA + 24 * (size_t)K_DIM + (size_t)(kt) * 128, la_ + 3072); \
  gload_lds16(pB + (size_t)(kt) * 128, lb_); \
  gload_lds16(pB + 8 * (size_t)K_DIM + (size_t)(kt) * 128, lb_ + 1024); \
  gload_lds16(pB + 16 * (size_t)K_DIM + (size_t)(kt) * 128, lb_ + 2048); \
  gload_lds16(pB + 24 * (size_t)K_DIM + (size_t)(kt) * 128, lb_ + 3072); \
} while (0)

#define WAIT_VM0 asm volatile("s_waitcnt vmcnt(0)" ::: "memory")
#define BAR() do { __builtin_amdgcn_s_barrier(); asm volatile("" ::: "memory"); } while (0)

__global__ __launch_bounds__(256, 2) void k_gemm8(const signed char* __restrict__ xq,
                                                  const signed char* __restrict__ wq,
                                                  const float* __restrict__ sc,
                                                  const float* __restrict__ sx,
                                                  const float* __restrict__ bias,
                                                  float* __restrict__ out) {
  __shared__ __align__(16) unsigned char sh[32768];  // 32 KiB single buffer

  const int nwg = gridDim.x;                 // 5504, % 8 == 0 -> bijective
  int bid = blockIdx.x;
  int swz = (bid & 7) * (nwg >> 3) + (bid >> 3);
  const int ntn = N_DIM / 128;               // 86
  int mt = swz / ntn;                        // 0..63 (M tiles of 128)
  int nt = swz % ntn;                        // 0..85 (N tiles of 128)

  const int tid = threadIdx.x;
  const int w = tid >> 6;        // wave 0..3
  const int lane = tid & 63;
  const int wm = w >> 1;         // 0..1: M half (64 rows)
  const int wn = w & 1;          // 0..1: N half (64 cols)
  const int fr = lane & 15;
  const int fq = lane >> 4;
  const int r7 = fr & 7;

  // staging source: per-lane pre-swizzled (involution slot^row), rows of 128 B
  const int srow = lane >> 3;                 // 0..7
  const int sslot = (lane & 7) ^ srow;        // 16B slot within the 128B row
  const size_t goff = (size_t)srow * K_DIM + (size_t)sslot * 16;
  const signed char* pA = xq + (size_t)(mt * 128 + w * 32) * K_DIM + goff;
  const signed char* pB = wq + (size_t)(nt * 128 + w * 32) * K_DIM + goff;

  // fragment byte offsets (ks0); ks1 = ^64 (slot = (ks*4+fq) ^ r7)
  const int swb = (fq ^ r7) << 4;
  const int aoff0 = (wm * 64 + 0 * 16 + fr) * 128 + swb;
  const int aoff1 = (wm * 64 + 1 * 16 + fr) * 128 + swb;
  const int aoff2 = (wm * 64 + 2 * 16 + fr) * 128 + swb;
  const int aoff3 = (wm * 64 + 3 * 16 + fr) * 128 + swb;
  const int boff0 = (wn * 64 + 0 * 16 + fr) * 128 + swb;
  const int boff1 = (wn * 64 + 1 * 16 + fr) * 128 + swb;
  const int boff2 = (wn * 64 + 2 * 16 + fr) * 128 + swb;
  const int boff3 = (wn * 64 + 3 * 16 + fr) * 128 + swb;

  const int c0 = nt * 128 + wn * 64 + fr;    // this lane's base output column

  i32x4 acci[4][4];                          // written by MFMA_FIRST each tile
  f32x4 accf[4][4] = {};
  i32x4 af[4], bf[4];
  const i32x4 zq4 = {0, 0, 0, 0};

  // prologue: stage tile 0
  STAGE_ALL(0);

  for (int t = 0; t < 32; ++t) {
    WAIT_VM0;      // staged tile landed
    BAR();
    // group scales for this tile (group == tile since BK = 128 = GROUPSIZE)
    float sg0 = sc[(size_t)t * N_DIM + c0 + 0];
    float sg1 = sc[(size_t)t * N_DIM + c0 + 16];
    float sg2 = sc[(size_t)t * N_DIM + c0 + 32];
    float sg3 = sc[(size_t)t * N_DIM + c0 + 48];
    LOADF(0);
    MFMA_FIRST();
    LOADF(1);
    MFMA_SECOND();
    // group end: scale i32 partials into f32 accumulators
    #pragma unroll
    for (int mi = 0; mi < 4; ++mi) {
      #pragma unroll
      for (int r = 0; r < 4; ++r) {
        accf[mi][0][r] += sg0 * (float)acci[mi][0][r];
        accf[mi][1][r] += sg1 * (float)acci[mi][1][r];
        accf[mi][2][r] += sg2 * (float)acci[mi][2][r];
        accf[mi][3][r] += sg3 * (float)acci[mi][3][r];
      }
    }
    BAR();         // all waves' reads of this tile complete
    if (t < 31) STAGE_ALL(t + 1);   // safe to overwrite
  }

  // epilogue: C/D layout col=lane&15, row=(lane>>4)*4+reg; out = sx[m]*accf + bias
  const int r0 = mt * 128 + wm * 64 + fq * 4;
  #pragma unroll
  for (int mi = 0; mi < 4; ++mi) {
    float sxr[4];
    #pragma unroll
    for (int r = 0; r < 4; ++r) sxr[r] = sx[r0 + mi * 16 + r];
    #pragma unroll
    for (int nj = 0; nj < 4; ++nj) {
      int col = c0 + nj * 16;
      float bv = bias[col];
      size_t base = (size_t)(r0 + mi * 16) * N_DIM + col;
      #pragma unroll
      for (int r = 0; r < 4; ++r)
        out[base + (size_t)r * N_DIM] = sxr[r] * accf[mi][nj][r] + bv;
    }
  }
}

// ---------------- fallback (ws too small): naive fp32 ----------------
__global__ void k_fallback(const float* __restrict__ x, const int* __restrict__ qw,
                           const int* __restrict__ qz, const float* __restrict__ sc,
                           const float* __restrict__ bias, float* __restrict__ out) {
  int n = blockIdx.x * blockDim.x + threadIdx.x;
  int m = blockIdx.y;
  const float* xr = x + (size_t)m * K_DIM;
  float acc = 0.f;
  for (int g = 0; g < 32; ++g) {
    float s = sc[g * N_DIM + n];
    int zq = (qz[g * (N_DIM / 8) + (n >> 3)] >> ((n & 7) * 4)) & 15;
    float zs = s * (float)zq;
    for (int k8 = g * 16; k8 < g * 16 + 16; ++k8) {
      int w = qw[(size_t)k8 * N_DIM + n];
      #pragma unroll
      for (int j = 0; j < 8; ++j) {
        float wf = s * (float)((w >> (4 * j)) & 15) - zs;
        acc += wf * xr[k8 * 8 + j];
      }
    }
  }
  out[(size_t)m * N_DIM + n] = acc + bias[n];
}

extern "C" void kernel_launch(void* const* d_in, const int* in_sizes, int n_in,
                              void* d_out, int out_size, void* d_ws, size_t ws_size,
                              hipStream_t stream) {
  const float* x  = (const float*)d_in[0];
  const int* qw   = (const int*)d_in[1];
  const int* qz   = (const int*)d_in[2];
  const float* sc = (const float*)d_in[3];
  const float* bias = (const float*)d_in[4];
  float* out = (float*)d_out;

  const size_t xq_bytes = (size_t)M_DIM * K_DIM;          // 33,554,432
  const size_t sx_bytes = (size_t)M_DIM * sizeof(float);  // 32,768
  const size_t wq_bytes = (size_t)N_DIM * K_DIM;          // 45,088,768
  const size_t need = xq_bytes + sx_bytes + wq_bytes;

  if (ws_size >= need) {
    signed char* xq = (signed char*)d_ws;
    float* sx = (float*)((char*)d_ws + xq_bytes);
    signed char* wq = (signed char*)((char*)d_ws + xq_bytes + sx_bytes);
    k_prep<<<dim3(M_DIM + 2752), dim3(256), 0, stream>>>(x, xq, sx, qw, qz, wq);
    k_gemm8<<<dim3((M_DIM / 128) * (N_DIM / 128)), dim3(256), 0, stream>>>(xq, wq, sc, sx, bias, out);
  } else {
    k_fallback<<<dim3(N_DIM / 256, M_DIM), dim3(256), 0, stream>>>(x, qw, qz, sc, bias, out);
  }
}

// Round 18
// 571.299 us; speedup vs baseline: 5.9221x; 1.0353x over previous
//
#include <hip/hip_runtime.h>
#include <hip/hip_bf16.h>
#include <stdint.h>

// QuantLinear GPTQ 4-bit: out[8192,11008] = x[8192,4096] . W[4096,11008] + bias
// i8 path: W' = (q - z) exact in i8; x per-row i8; per-group(128) scales folded
// on i32 partials; row scale at epilogue.
// FINAL (= r13, session best 574.6 us): 128x128 tile, BK=128 (= one scale
// group), 4 waves, double-buffered 64 KiB LDS -> 2 blocks/CU, zero-C first
// MFMA, fused prep. Session evidence this is near the structural limit:
//  - CU throughput ~915 cyc/tile vs LDS-pipe cost 770-1020 cyc/tile
//    (64 ds_read_b128 + 32KB DMA-write) -> ~85-110% LDS-pipe saturation.
//  - All escapes hit hard walls: B-direct global (r14 -75%, exposed L2 lat),
//    A-in-reg dbuf (r12 spill), 8-phase 256^2 i8 (r15 spill), 16 waves (r8
//    worse), single-buf more-blocks (r16 alloc-clamp spill / r17 neutral).
#define M_DIM 8192
#define K_DIM 4096
#define N_DIM 11008

typedef int i32x4 __attribute__((ext_vector_type(4)));
typedef float f32x4 __attribute__((ext_vector_type(4)));

typedef __attribute__((address_space(1))) const void global_cvoid;
typedef __attribute__((address_space(3))) void lds_void;

__device__ __forceinline__ void gload_lds16(const void* g, void* l) {
  // async global->LDS: each lane's 16B lands at lds_base + lane*16 (linear dest)
  __builtin_amdgcn_global_load_lds((global_cvoid*)g, (lds_void*)l, 16, 0, 0);
}

// ---------------- fused prep: quantize x (blocks < 8192) | unpack W (rest) ----------------
__global__ void k_prep(const float* __restrict__ x, signed char* __restrict__ xq,
                       float* __restrict__ sx, const int* __restrict__ qw,
                       const int* __restrict__ qz, signed char* __restrict__ wt) {
  if (blockIdx.x < M_DIM) {
    int m = blockIdx.x;
    int tx = threadIdx.x;                     // 256 threads, 16 floats each
    const float4* row = (const float4*)(x + (size_t)m * K_DIM);
    float4 v[4];
    float mx = 0.f;
    #pragma unroll
    for (int i = 0; i < 4; ++i) {
      v[i] = row[tx * 4 + i];
      mx = fmaxf(mx, fmaxf(fmaxf(fabsf(v[i].x), fabsf(v[i].y)),
                           fmaxf(fabsf(v[i].z), fabsf(v[i].w))));
    }
    #pragma unroll
    for (int off = 1; off < 64; off <<= 1)
      mx = fmaxf(mx, __shfl_xor(mx, off));
    __shared__ float wmx[4];
    if ((tx & 63) == 0) wmx[tx >> 6] = mx;
    __syncthreads();
    mx = fmaxf(fmaxf(wmx[0], wmx[1]), fmaxf(wmx[2], wmx[3]));
    mx = fmaxf(mx, 1e-20f);
    float scale = 127.0f / mx;
    if (tx == 0) sx[m] = mx / 127.0f;
    union { signed char c[16]; uint4 u; } p;
    #pragma unroll
    for (int i = 0; i < 4; ++i) {
      p.c[i * 4 + 0] = (signed char)(int)rintf(v[i].x * scale);
      p.c[i * 4 + 1] = (signed char)(int)rintf(v[i].y * scale);
      p.c[i * 4 + 2] = (signed char)(int)rintf(v[i].z * scale);
      p.c[i * 4 + 3] = (signed char)(int)rintf(v[i].w * scale);
    }
    ((uint4*)(xq + (size_t)m * K_DIM))[tx] = p.u;
  } else {
    int b = blockIdx.x - M_DIM;               // 2752 blocks: 43 n-blk x 64 k-blk
    int n = (b % 43) * 256 + threadIdx.x;
    int k8_0 = (b / 43) * 8;
    int g = (k8_0 * 8) >> 7;
    int zq = (qz[g * (N_DIM / 8) + (n >> 3)] >> ((n & 7) * 4)) & 15;
    #pragma unroll
    for (int i = 0; i < 8; ++i) {
      int k8 = k8_0 + i;
      int w = qw[(size_t)k8 * N_DIM + n];
      union { signed char c[8]; uint2 u; } r;
      #pragma unroll
      for (int j = 0; j < 8; ++j)
        r.c[j] = (signed char)(((w >> (4 * j)) & 15) - zq);
      *(uint2*)(wt + (size_t)n * K_DIM + (size_t)k8 * 8) = r.u;
    }
  }
}

// ---------------- i8 GEMM 128x128, BK=128, 4 waves, 2 blocks/CU ----------------
// Per tile: stage(t+1) -> reads ks0 -> 16 MFMA (C=0) -> reads ks1 -> 16 MFMA
// -> fold -> vmcnt(0) -> barrier. Re-stage of a buffer is >=1 drained barrier
// after its last read (audited r10/r11).

#define MFMA_FIRST() do { \
  __builtin_amdgcn_s_setprio(1); \
  acci[0][0] = __builtin_amdgcn_mfma_i32_16x16x64_i8(af[0], bf[0], zq4, 0, 0, 0); \
  acci[0][1] = __builtin_amdgcn_mfma_i32_16x16x64_i8(af[0], bf[1], zq4, 0, 0, 0); \
  acci[0][2] = __builtin_amdgcn_mfma_i32_16x16x64_i8(af[0], bf[2], zq4, 0, 0, 0); \
  acci[0][3] = __builtin_amdgcn_mfma_i32_16x16x64_i8(af[0], bf[3], zq4, 0, 0, 0); \
  acci[1][0] = __builtin_amdgcn_mfma_i32_16x16x64_i8(af[1], bf[0], zq4, 0, 0, 0); \
  acci[1][1] = __builtin_amdgcn_mfma_i32_16x16x64_i8(af[1], bf[1], zq4, 0, 0, 0); \
  acci[1][2] = __builtin_amdgcn_mfma_i32_16x16x64_i8(af[1], bf[2], zq4, 0, 0, 0); \
  acci[1][3] = __builtin_amdgcn_mfma_i32_16x16x64_i8(af[1], bf[3], zq4, 0, 0, 0); \
  acci[2][0] = __builtin_amdgcn_mfma_i32_16x16x64_i8(af[2], bf[0], zq4, 0, 0, 0); \
  acci[2][1] = __builtin_amdgcn_mfma_i32_16x16x64_i8(af[2], bf[1], zq4, 0, 0, 0); \
  acci[2][2] = __builtin_amdgcn_mfma_i32_16x16x64_i8(af[2], bf[2], zq4, 0, 0, 0); \
  acci[2][3] = __builtin_amdgcn_mfma_i32_16x16x64_i8(af[2], bf[3], zq4, 0, 0, 0); \
  acci[3][0] = __builtin_amdgcn_mfma_i32_16x16x64_i8(af[3], bf[0], zq4, 0, 0, 0); \
  acci[3][1] = __builtin_amdgcn_mfma_i32_16x16x64_i8(af[3], bf[1], zq4, 0, 0, 0); \
  acci[3][2] = __builtin_amdgcn_mfma_i32_16x16x64_i8(af[3], bf[2], zq4, 0, 0, 0); \
  acci[3][3] = __builtin_amdgcn_mfma_i32_16x16x64_i8(af[3], bf[3], zq4, 0, 0, 0); \
  __builtin_amdgcn_s_setprio(0); \
} while (0)

#define MFMA_SECOND() do { \
  __builtin_amdgcn_s_setprio(1); \
  acci[0][0] = __builtin_amdgcn_mfma_i32_16x16x64_i8(af[0], bf[0], acci[0][0], 0, 0, 0); \
  acci[0][1] = __builtin_amdgcn_mfma_i32_16x16x64_i8(af[0], bf[1], acci[0][1], 0, 0, 0); \
  acci[0][2] = __builtin_amdgcn_mfma_i32_16x16x64_i8(af[0], bf[2], acci[0][2], 0, 0, 0); \
  acci[0][3] = __builtin_amdgcn_mfma_i32_16x16x64_i8(af[0], bf[3], acci[0][3], 0, 0, 0); \
  acci[1][0] = __builtin_amdgcn_mfma_i32_16x16x64_i8(af[1], bf[0], acci[1][0], 0, 0, 0); \
  acci[1][1] = __builtin_amdgcn_mfma_i32_16x16x64_i8(af[1], bf[1], acci[1][1], 0, 0, 0); \
  acci[1][2] = __builtin_amdgcn_mfma_i32_16x16x64_i8(af[1], bf[2], acci[1][2], 0, 0, 0); \
  acci[1][3] = __builtin_amdgcn_mfma_i32_16x16x64_i8(af[1], bf[3], acci[1][3], 0, 0, 0); \
  acci[2][0] = __builtin_amdgcn_mfma_i32_16x16x64_i8(af[2], bf[0], acci[2][0], 0, 0, 0); \
  acci[2][1] = __builtin_amdgcn_mfma_i32_16x16x64_i8(af[2], bf[1], acci[2][1], 0, 0, 0); \
  acci[2][2] = __builtin_amdgcn_mfma_i32_16x16x64_i8(af[2], bf[2], acci[2][2], 0, 0, 0); \
  acci[2][3] = __builtin_amdgcn_mfma_i32_16x16x64_i8(af[2], bf[3], acci[2][3], 0, 0, 0); \
  acci[3][0] = __builtin_amdgcn_mfma_i32_16x16x64_i8(af[3], bf[0], acci[3][0], 0, 0, 0); \
  acci[3][1] = __builtin_amdgcn_mfma_i32_16x16x64_i8(af[3], bf[1], acci[3][1], 0, 0, 0); \
  acci[3][2] = __builtin_amdgcn_mfma_i32_16x16x64_i8(af[3], bf[2], acci[3][2], 0, 0, 0); \
  acci[3][3] = __builtin_amdgcn_mfma_i32_16x16x64_i8(af[3], bf[3], acci[3][3], 0, 0, 0); \
  __builtin_amdgcn_s_setprio(0); \
} while (0)

// A(4) + B(4) fragments for ks-slice of buffer buf (byte ^= ks*64 walks slot)
#define LOADF(buf, ks) do { \
  const unsigned char* base_ = sh + (buf) * 32768; \
  af[0] = *(const i32x4*)(const void*)(base_ + (aoff0 ^ ((ks) << 6))); \
  af[1] = *(const i32x4*)(const void*)(base_ + (aoff1 ^ ((ks) << 6))); \
  af[2] = *(const i32x4*)(const void*)(base_ + (aoff2 ^ ((ks) << 6))); \
  af[3] = *(const i32x4*)(const void*)(base_ + (aoff3 ^ ((ks) << 6))); \
  bf[0] = *(const i32x4*)(const void*)(base_ + 16384 + (boff0 ^ ((ks) << 6))); \
  bf[1] = *(const i32x4*)(const void*)(base_ + 16384 + (boff1 ^ ((ks) << 6))); \
  bf[2] = *(const i32x4*)(const void*)(base_ + 16384 + (boff2 ^ ((ks) << 6))); \
  bf[3] = *(const i32x4*)(const void*)(base_ + 16384 + (boff3 ^ ((ks) << 6))); \
} while (0)

// stage tile kt into buffer buf: 4 A-gloads + 4 B-gloads per wave
#define STAGE_ALL(buf, kt) do { \
  unsigned char* la_ = sh + (buf) * 32768 + w * 4096; \
  unsigned char* lb_ = la_ + 16384; \
  gload_lds16(pA + (size_t)(kt) * 128, la_); \
  gload_lds16(pA + 8 * (size_t)K_DIM + (size_t)(kt) * 128, la_ + 1024); \
  gload_lds16(pA + 16 * (size_t)K_DIM + (size_t)(kt) * 128, la_ + 2048); \
  gload_lds16(pA + 24 * (size_t)K_DIM + (size_t)(kt) * 128, la_ + 3072); \
  gload_lds16(pB + (size_t)(kt) * 128, lb_); \
  gload_lds16(pB + 8 * (size_t)K_DIM + (size_t)(kt) * 128, lb_ + 1024); \
  gload_lds16(pB + 16 * (size_t)K_DIM + (size_t)(kt) * 128, lb_ + 2048); \
  gload_lds16(pB + 24 * (size_t)K_DIM + (size_t)(kt) * 128, lb_ + 3072); \
} while (0)

#define WAIT_VM0 asm volatile("s_waitcnt vmcnt(0)" ::: "memory")
#define BAR() do { __builtin_amdgcn_s_barrier(); asm volatile("" ::: "memory"); } while (0)

__global__ __launch_bounds__(256, 2) void k_gemm8(const signed char* __restrict__ xq,
                                                  const signed char* __restrict__ wq,
                                                  const float* __restrict__ sc,
                                                  const float* __restrict__ sx,
                                                  const float* __restrict__ bias,
                                                  float* __restrict__ out) {
  __shared__ __align__(16) unsigned char sh[2 * 32768];  // 64 KiB -> 2 blocks/CU

  const int nwg = gridDim.x;                 // 5504, % 8 == 0 -> bijective
  int bid = blockIdx.x;
  int swz = (bid & 7) * (nwg >> 3) + (bid >> 3);
  const int ntn = N_DIM / 128;               // 86
  int mt = swz / ntn;                        // 0..63 (M tiles of 128)
  int nt = swz % ntn;                        // 0..85 (N tiles of 128)

  const int tid = threadIdx.x;
  const int w = tid >> 6;        // wave 0..3
  const int lane = tid & 63;
  const int wm = w >> 1;         // 0..1: M half (64 rows)
  const int wn = w & 1;          // 0..1: N half (64 cols)
  const int fr = lane & 15;
  const int fq = lane >> 4;
  const int r7 = fr & 7;

  // staging source: per-lane pre-swizzled (involution slot^row), rows of 128 B
  const int srow = lane >> 3;                 // 0..7
  const int sslot = (lane & 7) ^ srow;        // 16B slot within the 128B row
  const size_t goff = (size_t)srow * K_DIM + (size_t)sslot * 16;
  const signed char* pA = xq + (size_t)(mt * 128 + w * 32) * K_DIM + goff;
  const signed char* pB = wq + (size_t)(nt * 128 + w * 32) * K_DIM + goff;

  // fragment byte offsets (ks0); ks1 = ^64 (slot = (ks*4+fq) ^ r7)
  const int swb = (fq ^ r7) << 4;
  const int aoff0 = (wm * 64 + 0 * 16 + fr) * 128 + swb;
  const int aoff1 = (wm * 64 + 1 * 16 + fr) * 128 + swb;
  const int aoff2 = (wm * 64 + 2 * 16 + fr) * 128 + swb;
  const int aoff3 = (wm * 64 + 3 * 16 + fr) * 128 + swb;
  const int boff0 = (wn * 64 + 0 * 16 + fr) * 128 + swb;
  const int boff1 = (wn * 64 + 1 * 16 + fr) * 128 + swb;
  const int boff2 = (wn * 64 + 2 * 16 + fr) * 128 + swb;
  const int boff3 = (wn * 64 + 3 * 16 + fr) * 128 + swb;

  const int c0 = nt * 128 + wn * 64 + fr;    // this lane's base output column

  i32x4 acci[4][4];                          // written by MFMA_FIRST each tile
  f32x4 accf[4][4] = {};
  i32x4 af[4], bf[4];
  const i32x4 zq4 = {0, 0, 0, 0};

  // prologue: stage tile 0 into buf0
  STAGE_ALL(0, 0);
  WAIT_VM0;
  BAR();

  for (int t = 0; t < 32; ++t) {
    int buf = t & 1;
    if (t < 31) STAGE_ALL(buf ^ 1, t + 1);
    // group scales for this tile (group == tile since BK = 128 = GROUPSIZE)
    float sg0 = sc[(size_t)t * N_DIM + c0 + 0];
    float sg1 = sc[(size_t)t * N_DIM + c0 + 16];
    float sg2 = sc[(size_t)t * N_DIM + c0 + 32];
    float sg3 = sc[(size_t)t * N_DIM + c0 + 48];
    LOADF(buf, 0);
    MFMA_FIRST();
    LOADF(buf, 1);
    MFMA_SECOND();
    // group end: scale i32 partials into f32 accumulators
    #pragma unroll
    for (int mi = 0; mi < 4; ++mi) {
      #pragma unroll
      for (int r = 0; r < 4; ++r) {
        accf[mi][0][r] += sg0 * (float)acci[mi][0][r];
        accf[mi][1][r] += sg1 * (float)acci[mi][1][r];
        accf[mi][2][r] += sg2 * (float)acci[mi][2][r];
        accf[mi][3][r] += sg3 * (float)acci[mi][3][r];
      }
    }
    WAIT_VM0;      // next tile's 8 gloads (issued at top) have landed
    BAR();
  }

  // epilogue: C/D layout col=lane&15, row=(lane>>4)*4+reg; out = sx[m]*accf + bias
  const int r0 = mt * 128 + wm * 64 + fq * 4;
  #pragma unroll
  for (int mi = 0; mi < 4; ++mi) {
    float sxr[4];
    #pragma unroll
    for (int r = 0; r < 4; ++r) sxr[r] = sx[r0 + mi * 16 + r];
    #pragma unroll
    for (int nj = 0; nj < 4; ++nj) {
      int col = c0 + nj * 16;
      float bv = bias[col];
      size_t base = (size_t)(r0 + mi * 16) * N_DIM + col;
      #pragma unroll
      for (int r = 0; r < 4; ++r)
        out[base + (size_t)r * N_DIM] = sxr[r] * accf[mi][nj][r] + bv;
    }
  }
}

// ---------------- fallback (ws too small): naive fp32 ----------------
__global__ void k_fallback(const float* __restrict__ x, const int* __restrict__ qw,
                           const int* __restrict__ qz, const float* __restrict__ sc,
                           const float* __restrict__ bias, float* __restrict__ out) {
  int n = blockIdx.x * blockDim.x + threadIdx.x;
  int m = blockIdx.y;
  const float* xr = x + (size_t)m * K_DIM;
  float acc = 0.f;
  for (int g = 0; g < 32; ++g) {
    float s = sc[g * N_DIM + n];
    int zq = (qz[g * (N_DIM / 8) + (n >> 3)] >> ((n & 7) * 4)) & 15;
    float zs = s * (float)zq;
    for (int k8 = g * 16; k8 < g * 16 + 16; ++k8) {
      int w = qw[(size_t)k8 * N_DIM + n];
      #pragma unroll
      for (int j = 0; j < 8; ++j) {
        float wf = s * (float)((w >> (4 * j)) & 15) - zs;
        acc += wf * xr[k8 * 8 + j];
      }
    }
  }
  out[(size_t)m * N_DIM + n] = acc + bias[n];
}

extern "C" void kernel_launch(void* const* d_in, const int* in_sizes, int n_in,
                              void* d_out, int out_size, void* d_ws, size_t ws_size,
                              hipStream_t stream) {
  const float* x  = (const float*)d_in[0];
  const int* qw   = (const int*)d_in[1];
  const int* qz   = (const int*)d_in[2];
  const float* sc = (const float*)d_in[3];
  const float* bias = (const float*)d_in[4];
  float* out = (float*)d_out;

  const size_t xq_bytes = (size_t)M_DIM * K_DIM;          // 33,554,432
  const size_t sx_bytes = (size_t)M_DIM * sizeof(float);  // 32,768
  const size_t wq_bytes = (size_t)N_DIM * K_DIM;          // 45,088,768
  const size_t need = xq_bytes + sx_bytes + wq_bytes;

  if (ws_size >= need) {
    signed char* xq = (signed char*)d_ws;
    float* sx = (float*)((char*)d_ws + xq_bytes);
    signed char* wq = (signed char*)((char*)d_ws + xq_bytes + sx_bytes);
    k_prep<<<dim3(M_DIM + 2752), dim3(256), 0, stream>>>(x, xq, sx, qw, qz, wq);
    k_gemm8<<<dim3((M_DIM / 128) * (N_DIM / 128)), dim3(256), 0, stream>>>(xq, wq, sc, sx, bias, out);
  } else {
    k_fallback<<<dim3(N_DIM / 256, M_DIM), dim3(256), 0, stream>>>(x, qw, qz, sc, bias, out);
  }
}